// Round 16
// baseline (911.771 us; speedup 1.0000x reference)
//
#include <hip/hip_runtime.h>

// Problem geometry: B=8, H=512, W=512, HID=64, T=16.
#define HH 512
#define WW 512
#define WPR 16                     // u32 words per full-width row
#define RO 16                      // owned rows per producer block
#define HALO 15                    // T-1 steps of temporal blocking
#define ROWS (RO + 2 * HALO)       // 46 tile rows
#define FRAME_WORDS (8 * HH * WPR) // 65536 u32 per bit-frame (B=8)
#define NPROD 256                  // producer blocks (dispatched FIRST)
#define NCONS 768                  // consumer blocks
#define CHUNK 683                  // ceil(524288 float4 / NCONS)

// ---------------------------------------------------------------------------
// ONE persistent kernel, 1024 blocks x 256 threads = 4 blocks/CU (9 KiB LDS,
// <=128 VGPR by __launch_bounds__(256,4)) -> all blocks co-resident; and
// producers never wait on consumers, so forward progress is unconditional.
//
// Producers (blocks 0..255; 8 images x 32 bands of 16 rows): build rule +
// pair-LUT (byte-identical to the build verified absmax 0.0 in rounds 1-15),
// self-pack their full-width 46-row f0 slab (R8-verified ballot pack) + emit
// frame-0 floats, then 15 bit-steps (R8-evolve verbatim compute). Owned words
// go to global bit-frames via AGENT-scope atomic stores (cross-XCD coherent);
// after vmcnt(0)+barrier, lane 0 bumps ready[t].
//
// Consumers (blocks 256..1023): for each frame, lane 0 spins on ready[f]==256
// (acquire, s_sleep-throttled), then the block streams its 683-float4 chunk —
// a continuous fillBuffer-shaped write stream overlapping later production.
// ---------------------------------------------------------------------------
__global__ __launch_bounds__(256, 4) void fused(const float* __restrict__ f0,
                                                const float* __restrict__ W1,
                                                const float* __restrict__ b1,
                                                const float* __restrict__ W2,
                                                const float* __restrict__ b2,
                                                int hid, float* __restrict__ out,
                                                int n, int T,
                                                int* __restrict__ ready,
                                                unsigned int* __restrict__ frames) {
    __shared__ unsigned int rule[512];
    __shared__ unsigned int lutp[256];
    __shared__ unsigned int bufA[ROWS * WPR];
    __shared__ unsigned int bufB[ROWS * WPR];

    const int tid = threadIdx.x;

    if (blockIdx.x < NPROD) {
        // ================= PRODUCER =================
        const int rg = blockIdx.x & 31;
        const int b  = blockIdx.x >> 5;
        const int r0 = rg * RO;                 // first owned global row

        // rule table — byte-identical math to the verified build (absmax 0).
        for (int p = tid; p < 512; p += 256) {
            float logit = b2[0];
            for (int k = 0; k < hid; ++k) {
                float a = b1[k];
#pragma unroll
                for (int nn = 0; nn < 9; ++nn)
                    if (p & (1 << nn)) a += W1[nn * hid + k];
                logit += fmaxf(a, 0.0f) * W2[k];
            }
            rule[p] = (logit > 0.0f) ? 1u : 0u;
        }
        __syncthreads();

        // pair-LUT (verified R2-R15): idx12 = u4|m4<<4|d4<<8 -> 2 cells.
        {
            unsigned int wv = 0;
#pragma unroll
            for (int k = 0; k < 16; ++k) {
                unsigned int e = (unsigned int)tid * 16u + k;
                unsigned int u = e & 15u, mm = (e >> 4) & 15u, d = (e >> 8) & 15u;
                unsigned int i0 = (u & 7u) | ((mm & 7u) << 3) | ((d & 7u) << 6);
                unsigned int i1 = (u >> 1) | ((mm >> 1) << 3) | ((d >> 1) << 6);
                wv |= (rule[i0] | (rule[i1] << 1)) << (2 * k);
            }
            lutp[tid] = wv;
        }

        // self-pack 46x512 f0 slab + frame-0 verbatim floats (R8-verified:
        // stride 256 is wave-multiple; 512%64==0 so no wave straddles a row;
        // lane0/lane32 both store at word c>>5; 46*512 = 92*256 exact).
        {
            const float* f0b = f0 + (size_t)b * (HH * WW);
            float* out0 = out + (size_t)b * (HH * WW);
            const int lane = tid & 63;
            for (int i = tid; i < ROWS * WW; i += 256) {
                int l = i >> 9, c = i & 511;
                int gr = (r0 - HALO + l) & (HH - 1);
                float v = f0b[(size_t)gr * WW + c];
                unsigned long long m = __ballot(v > 0.5f);
                if (lane == 0)  bufA[l * WPR + (c >> 5)] = (unsigned int)m;
                if (lane == 32) bufA[l * WPR + (c >> 5)] = (unsigned int)(m >> 32);
                if (l >= HALO && l < HALO + RO)
                    out0[(size_t)gr * WW + c] = v;
            }
        }
        __syncthreads();

        unsigned int* oldb = bufA;
        unsigned int* newb = bufB;

        for (int t = 1; t < T; ++t) {
            const int ntask = (ROWS - 2 * t) * WPR;   // rows [t, ROWS-t)
            for (int task = tid; task < ntask; task += 256) {
                const int lq = task >> 4;
                const int w  = task & 15;
                const int l  = t + lq;
                const unsigned int* Ru = oldb + (l - 1) * WPR;
                const unsigned int* Rm = oldb + l * WPR;
                const unsigned int* Rd = oldb + (l + 1) * WPR;
                const int wl = (w + 15) & 15, wn = (w + 1) & 15;  // full-width wrap
                unsigned long long eu = ((((unsigned long long)Ru[wn] << 32) | Ru[w]) << 1) | (Ru[wl] >> 31);
                unsigned long long em = ((((unsigned long long)Rm[wn] << 32) | Rm[w]) << 1) | (Rm[wl] >> 31);
                unsigned long long ed = ((((unsigned long long)Rd[wn] << 32) | Rd[w]) << 1) | (Rd[wl] >> 31);
                unsigned int ow = 0;
#pragma unroll
                for (int j = 0; j < 16; ++j) {
                    unsigned int idx = (unsigned int)((eu >> (2 * j)) & 15ull)
                                     | ((unsigned int)((em >> (2 * j)) & 15ull) << 4)
                                     | ((unsigned int)((ed >> (2 * j)) & 15ull) << 8);
                    ow |= ((lutp[idx >> 4] >> ((idx & 15u) * 2)) & 3u) << (2 * j);
                }
                newb[l * WPR + w] = ow;
                if (l >= HALO && l < HALO + RO)   // owned word -> bit-frame
                    __hip_atomic_store(&frames[(size_t)(t - 1) * FRAME_WORDS
                                               + b * (HH * WPR)
                                               + (size_t)(r0 + l - HALO) * WPR + w],
                                       ow, __ATOMIC_RELAXED, __HIP_MEMORY_SCOPE_AGENT);
            }
            // drain this wave's frame stores, sync block, publish frame t.
            asm volatile("s_waitcnt vmcnt(0) lgkmcnt(0)" ::: "memory");
            __builtin_amdgcn_s_barrier();
            __builtin_amdgcn_sched_barrier(0);
            if (tid == 0) atomicAdd(&ready[t], 1);   // device-scope (m20)
            unsigned int* tmp = oldb; oldb = newb; newb = tmp;
        }
    } else {
        // ================= CONSUMER =================
        const int cb   = blockIdx.x - NPROD;          // 0..767
        const int nf4  = n >> 2;                      // 524288 float4/frame
        const int base = cb * CHUNK;
        const int lim  = (base + CHUNK < nf4) ? base + CHUNK : nf4;

        for (int f = 1; f < T; ++f) {
            if (tid == 0) {
                while (__hip_atomic_load(&ready[f], __ATOMIC_ACQUIRE,
                                         __HIP_MEMORY_SCOPE_AGENT) < NPROD)
                    __builtin_amdgcn_s_sleep(2);
            }
            __syncthreads();
            const unsigned int* fr = frames + (size_t)(f - 1) * FRAME_WORDS;
            float4* outf = (float4*)out + (size_t)f * nf4;
#pragma unroll
            for (int i = 0; i < 3; ++i) {
                int idx = base + i * 256 + tid;
                if (idx < lim) {
                    unsigned int wv = __hip_atomic_load(&fr[idx >> 3],
                                                        __ATOMIC_RELAXED,
                                                        __HIP_MEMORY_SCOPE_AGENT);
                    unsigned int nib = (wv >> ((idx & 7) * 4)) & 15u;
                    float4 v;
                    v.x = (float)(nib & 1u);
                    v.y = (float)((nib >> 1) & 1u);
                    v.z = (float)((nib >> 2) & 1u);
                    v.w = (float)(nib >> 3);
                    outf[idx] = v;
                }
            }
        }
    }
}

// ---------------------------------------------------------------------------
// Launch: memsetAsync(ready) -> ONE fused dispatch.
// d_ws: [0, 64)    ready[16] flags (zeroed each call — harness doesn't)
//       [256, ...) bit-frames for steps 1..15 (15 * 256 KiB = 3.93 MB)
// ---------------------------------------------------------------------------
extern "C" void kernel_launch(void* const* d_in, const int* in_sizes, int n_in,
                              void* d_out, int out_size, void* d_ws, size_t ws_size,
                              hipStream_t stream) {
    const float* f0 = (const float*)d_in[0];
    const float* W1 = (const float*)d_in[1];
    const float* b1 = (const float*)d_in[2];
    const float* W2 = (const float*)d_in[3];
    const float* b2 = (const float*)d_in[4];
    float* out = (float*)d_out;

    const int n = in_sizes[0];        // B*1*H*W = 2,097,152
    const int hid = in_sizes[2];      // 64
    const int T = out_size / n;       // 16

    int* ready = (int*)d_ws;
    unsigned int* frames = (unsigned int*)((char*)d_ws + 256);

    hipMemsetAsync(ready, 0, 64, stream);
    fused<<<NPROD + NCONS, 256, 0, stream>>>(f0, W1, b1, W2, b2, hid, out, n, T,
                                             ready, frames);
}

// Round 17
// 70.549 us; speedup vs baseline: 12.9239x; 12.9239x over previous
//
#include <hip/hip_runtime.h>

// Problem geometry: B=8, H=512, W=512, HID=64, T=16.
#define HH 512
#define WW 512
#define WPR 16                    // u32 words per global row
#define RO 8                      // owned rows per block (R10 had 16)
#define HALO 15                   // T-1 steps of temporal blocking
#define ROWS (RO + 2 * HALO)      // 38 rows staged in LDS
#define OW 8                      // owned words per block (256 cols)
#define TW 10                     // tile words = owned + 1 halo word each side
// Halo-word correctness: dependency cone grows 1 bit/step; clamp garbage in
// the +/-1 halo words never reaches owned bits (verified rounds 2-4,6-15).

// lgkm-only barrier: waits only on LDS ops; global float stores stay in
// flight across steps. sched_barrier(0) REMOVED this round (guide m141:
// order-pinning defeats compiler scheduling; s_barrier intrinsic already
// blocks LDS-op motion).
#define STEP_BARRIER() do {                                   \
    asm volatile("s_waitcnt lgkmcnt(0)" ::: "memory");        \
    __builtin_amdgcn_s_barrier();                             \
} while (0)

// ---------------------------------------------------------------------------
// Kernel 1 (R10-verbatim, verified absmax 0): out[0]=f0; bit-pack field;
// blocks 0..63 build the 64K-entry quad-LUT (idx16 = 4-bit col-windows of
// rows l-1..l+2 -> 4 bits: cells (2j,2j+1) of rows l and l+1), 8 entries/u32,
// 32 KiB total.
// ---------------------------------------------------------------------------
__global__ __launch_bounds__(512) void init_pack(const float* __restrict__ f0,
                                                 const float* __restrict__ W1,
                                                 const float* __restrict__ b1,
                                                 const float* __restrict__ W2,
                                                 const float* __restrict__ b2,
                                                 int hid,
                                                 float* __restrict__ out,
                                                 unsigned long long* __restrict__ field,
                                                 unsigned int* __restrict__ lut16g) {
    __shared__ unsigned int rule[512];
    const int tid = threadIdx.x;
    int c = blockIdx.x * 512 + tid;
    float v = f0[c];
    out[c] = v;
    unsigned long long m = __ballot(v > 0.5f);
    if ((tid & 63) == 0) field[c >> 6] = m;

    if (blockIdx.x < 64) {
        {   // rule table — byte-identical math to the verified build.
            int p = tid;  // 0..511
            float logit = b2[0];
            for (int k = 0; k < hid; ++k) {
                float a = b1[k];
#pragma unroll
                for (int nn = 0; nn < 9; ++nn)
                    if (p & (1 << nn)) a += W1[nn * hid + k];
                logit += fmaxf(a, 0.0f) * W2[k];
            }
            rule[p] = (logit > 0.0f) ? 1u : 0u;
        }
        __syncthreads();
        if (tid < 128) {   // this block's 128-word slice of the quad-LUT
            int word = blockIdx.x * 128 + tid;
            unsigned int wv = 0;
#pragma unroll
            for (int k = 0; k < 8; ++k) {
                unsigned int e = (unsigned int)word * 8u + k;
                unsigned int a = e & 15u, b = (e >> 4) & 15u;
                unsigned int cc = (e >> 8) & 15u, d = (e >> 12) & 15u;
                unsigned int bit0 = rule[(a & 7u) | ((b & 7u) << 3) | ((cc & 7u) << 6)];
                unsigned int bit1 = rule[((a >> 1) & 7u) | (((b >> 1) & 7u) << 3) | (((cc >> 1) & 7u) << 6)];
                unsigned int bit2 = rule[(b & 7u) | ((cc & 7u) << 3) | ((d & 7u) << 6)];
                unsigned int bit3 = rule[((b >> 1) & 7u) | (((cc >> 1) & 7u) << 3) | (((d >> 1) & 7u) << 6)];
                wv |= (bit0 | (bit1 << 1) | (bit2 << 2) | (bit3 << 3)) << (4 * k);
            }
            lut16g[word] = wv;
        }
    }
}

// ---------------------------------------------------------------------------
// Kernel 2: quad-LUT at 4 blocks/CU (the untested grid cell). 1024 blocks
// (8 images x 64 row-groups x 2 col-groups) x 512 thr; LDS 35.8 KiB/block
// (32 KiB LUT + 2x 38x10 tile) -> 4 blocks/CU = 32 waves/CU. Per step:
// row-pair quad-LUT tasks ((19-t)*10 <= 180, one per thread, R10-verbatim
// math); lgkm-only barrier; one float4/thread emit (R8-verified pattern)
// streaming while the next step computes.
// ---------------------------------------------------------------------------
__global__ __launch_bounds__(512) void mega(const unsigned int* __restrict__ field,
                                            const unsigned int* __restrict__ lut16g,
                                            float* __restrict__ out,
                                            int n, int T) {
    __shared__ alignas(16) unsigned int lut16[8192];   // 32 KiB
    __shared__ unsigned int bufA[ROWS * TW];
    __shared__ unsigned int bufB[ROWS * TW];

    const int tid = threadIdx.x;
    const int cg = blockIdx.x & 1;
    const int rg = (blockIdx.x >> 1) & 63;
    const int b  = blockIdx.x >> 7;
    const int r0 = rg * RO;          // first owned global row
    const int q0 = cg * OW;          // first owned global word
    const int c0 = cg * (OW * 32);   // first owned global column

    // quad-LUT: 2048 uint4 loads (coalesced; L2-broadcast across blocks).
    for (int i = tid; i < 2048; i += 512)
        ((uint4*)lut16)[i] = ((const uint4*)lut16g)[i];
    // bit tile load (wrap in H via &511, in W via &15) — verified R3/R8/R10.
    {
        const unsigned int* F = field + b * (HH * WPR);
        for (int i = tid; i < ROWS * TW; i += 512) {
            int l = i / TW, tw = i - l * TW;
            int g  = (r0 - HALO + l) & (HH - 1);
            int gw = (q0 - 1 + tw) & (WPR - 1);
            bufA[i] = F[g * WPR + gw];
        }
    }
    __syncthreads();

    unsigned int* oldb = bufA;
    unsigned int* newb = bufB;
    float* outb = out + (size_t)b * (HH * WW);

    for (int t = 1; t < T; ++t) {
        // row-pair tasks: pairs tile valid rows [t, 38-t) (even count 38-2t).
        const int npairs = 19 - t;
        if (tid < npairs * TW) {
            const int pr = tid / TW;
            const int w  = tid - pr * TW;
            const int l  = t + 2 * pr;                  // first output row
            const unsigned int* Ra = oldb + (l - 1) * TW;
            const unsigned int* Rb = oldb + l * TW;
            const unsigned int* Rc = oldb + (l + 1) * TW;
            const unsigned int* Rd = oldb + (l + 2) * TW;
            const int wl = (w == 0) ? 0 : w - 1;        // garbage-safe (cone)
            const int wn = (w == TW - 1) ? TW - 1 : w + 1;
            unsigned long long ea = ((((unsigned long long)Ra[wn] << 32) | Ra[w]) << 1) | (Ra[wl] >> 31);
            unsigned long long eb = ((((unsigned long long)Rb[wn] << 32) | Rb[w]) << 1) | (Rb[wl] >> 31);
            unsigned long long ec = ((((unsigned long long)Rc[wn] << 32) | Rc[w]) << 1) | (Rc[wl] >> 31);
            unsigned long long ed = ((((unsigned long long)Rd[wn] << 32) | Rd[w]) << 1) | (Rd[wl] >> 31);
            unsigned int owb = 0, owc = 0;
#pragma unroll
            for (int j = 0; j < 16; ++j) {
                unsigned int idx = (unsigned int)((ea >> (2 * j)) & 15ull)
                                 | ((unsigned int)((eb >> (2 * j)) & 15ull) << 4)
                                 | ((unsigned int)((ec >> (2 * j)) & 15ull) << 8)
                                 | ((unsigned int)((ed >> (2 * j)) & 15ull) << 12);
                unsigned int ent = (lut16[idx >> 3] >> ((idx & 7u) * 4)) & 15u;
                owb |= (ent & 3u) << (2 * j);
                owc |= ((ent >> 2) & 3u) << (2 * j);
            }
            newb[l * TW + w] = owb;
            newb[(l + 1) * TW + w] = owc;
        }
        STEP_BARRIER();    // lgkm-only: newb complete, oldb reads done;
                           // frame stores from previous steps stay in flight.

        // emit step t: owned 8 rows x 256 cols = 512 float4 (exactly one per
        // thread, R8-verified pattern). Overlaps next step's compute (which
        // writes only oldb); ds_reads of newb complete by the NEXT barrier.
        float* outt = outb + (size_t)t * n;
        {
            int cell = tid * 4;                        // 0..2044, step 4
            int lr  = cell >> 8;                       // owned row 0..7
            int col = cell & 255;                      // owned col
            unsigned int wv = newb[(HALO + lr) * TW + 1 + (col >> 5)];
            unsigned int nib = (wv >> (col & 31)) & 15u;
            float4 v;
            v.x = (float)(nib & 1u);
            v.y = (float)((nib >> 1) & 1u);
            v.z = (float)((nib >> 2) & 1u);
            v.w = (float)(nib >> 3);
            *(float4*)(outt + (size_t)(r0 + lr) * WW + c0 + col) = v;
        }
        unsigned int* tmp = oldb; oldb = newb; newb = tmp;
    }
}

// ---------------------------------------------------------------------------
// Launch: init_pack -> mega (2 dispatches).
// d_ws: [0, 32768)            quad-LUT (8192 u32)
//       [32768, 32768 + n/8)  packed step-0 bit field (256 KiB)
// ---------------------------------------------------------------------------
extern "C" void kernel_launch(void* const* d_in, const int* in_sizes, int n_in,
                              void* d_out, int out_size, void* d_ws, size_t ws_size,
                              hipStream_t stream) {
    const float* f0 = (const float*)d_in[0];
    const float* W1 = (const float*)d_in[1];
    const float* b1 = (const float*)d_in[2];
    const float* W2 = (const float*)d_in[3];
    const float* b2 = (const float*)d_in[4];
    float* out = (float*)d_out;

    const int n = in_sizes[0];        // B*1*H*W = 2,097,152
    const int hid = in_sizes[2];      // 64
    const int T = out_size / n;       // 16
    const int B = n / (HH * WW);      // 8

    char* ws = (char*)d_ws;
    unsigned int* lut16g = (unsigned int*)ws;
    unsigned long long* fld = (unsigned long long*)(ws + 32768);

    init_pack<<<n / 512, 512, 0, stream>>>(f0, W1, b1, W2, b2, hid, out, fld, lut16g);
    mega<<<B * (HH / RO) * 2, 512, 0, stream>>>((const unsigned int*)fld, lut16g,
                                                out, n, T);
}